// Round 8
// baseline (290.312 us; speedup 1.0000x reference)
//
#include <hip/hip_runtime.h>
#include <hip/hip_bf16.h>

#define S 9216      // 96*96 spatial positions
#define C 256       // channels
#define NCT 6       // 256-col tiles per block (block covers 64 rows x 1536 cols)
#define SCH 1152    // s-chunk for rowsum/colmax kernels

typedef __bf16 bf16x8 __attribute__((ext_vector_type(8)));
typedef float f32x4 __attribute__((ext_vector_type(4)));
typedef unsigned short us8 __attribute__((ext_vector_type(8)));
typedef unsigned short us4 __attribute__((ext_vector_type(4)));

#define A2C 2.8853900817779268f   // 2*log2(e) = 2/ln2

__device__ __forceinline__ float bf2f(unsigned short u) {
    return __uint_as_float(((unsigned)u) << 16);
}
__device__ __forceinline__ unsigned short f2bfbits(float x) {
    __hip_bfloat16 h = __float2bfloat16(x);
    return *reinterpret_cast<unsigned short*>(&h);
}

// ---------------- mean of gt over spatial, per channel ----------------
__global__ __launch_bounds__(256) void k_mean(const float* __restrict__ gt,
                                              float* __restrict__ meanT) {
    const int c = blockIdx.x;
    const float* p = gt + (size_t)c * S;
    float s = 0.f;
    for (int i = threadIdx.x; i < S; i += 256) s += p[i];
    for (int m = 1; m < 64; m <<= 1) s += __shfl_xor(s, m, 64);
    __shared__ float red[4];
    if ((threadIdx.x & 63) == 0) red[threadIdx.x >> 6] = s;
    __syncthreads();
    if (threadIdx.x == 0)
        meanT[c] = (red[0] + red[1] + red[2] + red[3]) * (1.0f / S);
}

// ---------------- partial centered sum-of-squares over 32-channel parts ----
__global__ __launch_bounds__(256) void k_ssq(const float* __restrict__ img,
                                             const float* __restrict__ gt,
                                             const float* __restrict__ meanT,
                                             float* __restrict__ ssqP) {  // [16][S]
    __shared__ float sm[32];
    const int part = blockIdx.x & 7;
    const int sb   = blockIdx.x >> 3;
    const int t    = threadIdx.x;
    if (t < 32) sm[t] = meanT[part * 32 + t];
    __syncthreads();
    const int s = sb * 256 + t;
    float si = 0.f, st = 0.f;
    #pragma unroll 8
    for (int k = 0; k < 32; ++k) {
        const int c = part * 32 + k;
        const float m  = sm[k];
        const float di = img[(size_t)c * S + s] - m;
        const float dt = gt [(size_t)c * S + s] - m;
        si += di * di;
        st += dt * dt;
    }
    ssqP[(size_t)part * S + s]       = si;
    ssqP[(size_t)(part + 8) * S + s] = st;
}

// ---------------- write normalized bf16 A,B (transposed to [S][C]) --------
__global__ __launch_bounds__(256) void k_write(const float* __restrict__ img,
                                               const float* __restrict__ gt,
                                               const float* __restrict__ meanT,
                                               const float* __restrict__ ssqP,
                                               __hip_bfloat16* __restrict__ A,
                                               __hip_bfloat16* __restrict__ B) {
    __shared__ float sm[32];
    const int part = blockIdx.x & 7;
    const int sb   = blockIdx.x >> 3;
    const int t    = threadIdx.x;
    if (t < 32) sm[t] = meanT[part * 32 + t];
    __syncthreads();
    const int s = sb * 256 + t;
    float si = 0.f, st = 0.f;
    #pragma unroll
    for (int p = 0; p < 8; ++p) {
        si += ssqP[(size_t)p * S + s];
        st += ssqP[(size_t)(p + 8) * S + s];
    }
    const float ri = 1.0f / fmaxf(sqrtf(si), 1e-12f);
    const float rt = 1.0f / fmaxf(sqrtf(st), 1e-12f);
    const int c0 = part * 32;
    #pragma unroll
    for (int cc = 0; cc < 4; ++cc) {
        us8 va, vb;
        #pragma unroll
        for (int e = 0; e < 8; ++e) {
            const int c = c0 + cc * 8 + e;
            const float m = sm[cc * 8 + e];
            va[e] = f2bfbits((img[(size_t)c * S + s] - m) * ri);
            vb[e] = f2bfbits((gt [(size_t)c * S + s] - m) * rt);
        }
        *reinterpret_cast<us8*>(A + (size_t)s * C + c0 + cc * 8) = va;
        *reinterpret_cast<us8*>(B + (size_t)s * C + c0 + cc * 8) = vb;
    }
}

// ---------------- init reduction buffers ----------------
__global__ __launch_bounds__(256) void k_init(float* __restrict__ rowmin,
                                              float* __restrict__ rowsum,
                                              float* __restrict__ colmaxLog) {
    const int i = blockIdx.x * 256 + threadIdx.x;
    if (i < S) {
        rowmin[i]     = __uint_as_float(0x7f800000u);  // +inf
        rowsum[i]     = 0.f;
        colmaxLog[i]  = 0.f;   // biased log2 max; 0 == 2^-64 ~ 0
    }
}

// ---------------- GEMM pass: store raw^T + rowmin ----------------
// NO LDS, NO barriers. A fragments live in 128 VGPRs per lane (wave's 64
// rows x full K=256 = 32KB/wave, one-time load). B fragments are loaded
// global->reg per kt from L2 (A,B are 4.7MB each: cache-resident; staging
// them through LDS was pure overhead — the lockstep barrier structure held
// MfmaUtil at ~13% for 4 rounds straight). Waves are fully independent;
// the compiler software-pipelines B loads across the unrolled kt-loop.
// XCD-locality mapping keeps each XCD's co-resident B-slice ~3MB (<4MiB L2).
__global__ __launch_bounds__(256, 2) void k_gemm_store(const __hip_bfloat16* __restrict__ A,
                                                       const __hip_bfloat16* __restrict__ B,
                                                       float* __restrict__ rowmin,
                                                       __hip_bfloat16* __restrict__ Q) {
    const int lane = threadIdx.x & 63;
    const int wid  = threadIdx.x >> 6;
    // 864 blocks = 8 XCDs x (6 colGroups x 18 strips)
    const int orig = blockIdx.x;
    const int xcd  = orig & 7;
    const int q    = orig >> 3;                 // 0..107
    const int colGroup = q / 18;                // 0..5
    const int strip    = xcd * 18 + (q % 18);   // 0..143
    const int rowBase = strip * 64;
    const int cb0     = colGroup * 1536;

    const int frow = lane & 15;
    const int kgrp = lane >> 4;

    // ---- A fragments in registers: rows m*16+frow, k = kt*32 + kgrp*8
    bf16x8 a[4][8];
    #pragma unroll
    for (int m = 0; m < 4; ++m) {
        const __hip_bfloat16* ap = A + (size_t)(rowBase + m * 16 + frow) * C + kgrp * 8;
        #pragma unroll
        for (int kt = 0; kt < 8; ++kt)
            a[m][kt] = *reinterpret_cast<const bf16x8*>(ap + kt * 32);
    }

    for (int t = 0; t < NCT; ++t) {
        const int colBase = cb0 + t * 256 + wid * 64;
        const __hip_bfloat16* bp = B + (size_t)(colBase + frow) * C + kgrp * 8;

        f32x4 acc[4][4] = {};
        #pragma unroll
        for (int kt = 0; kt < 8; ++kt) {
            bf16x8 bfr[4];
            #pragma unroll
            for (int n = 0; n < 4; ++n)
                bfr[n] = *reinterpret_cast<const bf16x8*>(bp + (size_t)(n * 16) * C + kt * 32);
            #pragma unroll
            for (int m = 0; m < 4; ++m)
                #pragma unroll
                for (int n = 0; n < 4; ++n)
                    acc[m][n] = __builtin_amdgcn_mfma_f32_16x16x32_bf16(a[m][kt], bfr[n], acc[m][n], 0, 0, 0);
        }

        // ---- epilogue tile t: store raw^T + rowmin
        // C/D map: r_local = m*16 + kgrp*4 + q, col = colBase + n*16 + frow
        float vmin[4][4];
        #pragma unroll
        for (int m = 0; m < 4; ++m)
            #pragma unroll
            for (int qq = 0; qq < 4; ++qq) vmin[m][qq] = 1e30f;

        #pragma unroll
        for (int n = 0; n < 4; ++n) {
            const int cg = colBase + n * 16 + frow;
            #pragma unroll
            for (int m = 0; m < 4; ++m) {
                us4 pk;
                #pragma unroll
                for (int qq = 0; qq < 4; ++qq) {
                    const float raw = fmaxf(0.5f * (1.0f - acc[m][n][qq]), 0.0f);
                    vmin[m][qq] = fminf(vmin[m][qq], raw);
                    pk[qq] = f2bfbits(raw);
                }
                *reinterpret_cast<us4*>(Q + (size_t)cg * S + rowBase + m * 16 + kgrp * 4) = pk;
            }
        }
        #pragma unroll
        for (int m = 0; m < 4; ++m)
            #pragma unroll
            for (int qq = 0; qq < 4; ++qq) {
                float v = vmin[m][qq];
                v = fminf(v, __shfl_xor(v, 1, 64));
                v = fminf(v, __shfl_xor(v, 2, 64));
                v = fminf(v, __shfl_xor(v, 4, 64));
                v = fminf(v, __shfl_xor(v, 8, 64));
                if (frow == 0)
                    atomicMin((unsigned int*)&rowmin[rowBase + m * 16 + kgrp * 4 + qq],
                              __float_as_uint(v));
            }
    }
}

// ---------------- rowsum over s-chunks (exp2 form) ------------
__global__ __launch_bounds__(256) void k_rowsum(const __hip_bfloat16* __restrict__ Q,
                                                const float* __restrict__ rowmin,
                                                float* __restrict__ rowsum) {
    __shared__ float sBrN[64];   // -A2C / (rowmin+eps)
    __shared__ float srs[64];
    const int t  = threadIdx.x;
    const int r0 = (blockIdx.x >> 3) * 64;
    const int s0 = (blockIdx.x & 7) * SCH;
    if (t < 64) {
        sBrN[t] = -A2C / (rowmin[r0 + t] + 1e-5f);
        srs[t]  = 0.f;
    }
    __syncthreads();
    const int roct = (t & 7) * 8;
    const int ss   = t >> 3;          // 0..31
    float brn[8];
    #pragma unroll
    for (int j = 0; j < 8; ++j) brn[j] = sBrN[roct + j];
    const __hip_bfloat16* base = Q + r0 + roct;

    float sums[8] = {};
    #pragma unroll 4
    for (int i = 0; i < SCH / 32; ++i) {
        const int s = s0 + ss + i * 32;
        const us8 v = *reinterpret_cast<const us8*>(base + (size_t)s * S);
        #pragma unroll
        for (int j = 0; j < 8; ++j)
            sums[j] += exp2f(fmaf(brn[j], bf2f(v[j]), A2C));
    }
    #pragma unroll
    for (int j = 0; j < 8; ++j) {
        float x = sums[j];
        x += __shfl_xor(x, 8, 64);
        x += __shfl_xor(x, 16, 64);
        x += __shfl_xor(x, 32, 64);
        if ((t & 63) < 8) atomicAdd(&srs[roct + j], x);
    }
    __syncthreads();
    if (t < 64) atomicAdd(&rowsum[r0 + t], srs[t]);
}

// ---------------- colmax in LOG space (3 ops/elem, no exp) ----------------
__global__ __launch_bounds__(256) void k_colmax(const __hip_bfloat16* __restrict__ Q,
                                                const float* __restrict__ rowmin,
                                                const float* __restrict__ rowsum,
                                                float* __restrict__ colmaxLog) {
    __shared__ float sBrN[64];
    __shared__ float sCA[64];
    const int t  = threadIdx.x;
    const int r0 = (blockIdx.x >> 3) * 64;
    const int s0 = (blockIdx.x & 7) * SCH;
    if (t < 64) {
        sBrN[t] = -A2C / (rowmin[r0 + t] + 1e-5f);
        sCA[t]  = A2C + 64.0f - __log2f(rowsum[r0 + t]);
    }
    __syncthreads();
    const int roct = (t & 7) * 8;
    const int ss   = t >> 3;
    float brn[8], ca[8];
    #pragma unroll
    for (int j = 0; j < 8; ++j) { brn[j] = sBrN[roct + j]; ca[j] = sCA[roct + j]; }
    const __hip_bfloat16* base = Q + r0 + roct;

    #pragma unroll 4
    for (int i = 0; i < SCH / 32; ++i) {
        const int s = s0 + ss + i * 32;
        const us8 v = *reinterpret_cast<const us8*>(base + (size_t)s * S);
        float mx = -1e30f;
        #pragma unroll
        for (int j = 0; j < 8; ++j)
            mx = fmaxf(mx, fmaf(brn[j], bf2f(v[j]), ca[j]));
        mx = fmaxf(mx, __shfl_xor(mx, 1, 64));
        mx = fmaxf(mx, __shfl_xor(mx, 2, 64));
        mx = fmaxf(mx, __shfl_xor(mx, 4, 64));
        if ((t & 7) == 0)
            atomicMax((unsigned int*)&colmaxLog[s], __float_as_uint(fmaxf(mx, 0.0f)));
    }
}

// ---------------- final: loss = -log(mean_s 2^(cl[s]-64)) ----------------
__global__ __launch_bounds__(256) void k_final(const float* __restrict__ colmaxLog,
                                               float* __restrict__ out) {
    float s = 0.f;
    for (int i = threadIdx.x; i < S; i += 256) s += exp2f(colmaxLog[i]);
    for (int m = 1; m < 64; m <<= 1) s += __shfl_xor(s, m, 64);
    __shared__ float red[4];
    if ((threadIdx.x & 63) == 0) red[threadIdx.x >> 6] = s;
    __syncthreads();
    if (threadIdx.x == 0) {
        const float total = red[0] + red[1] + red[2] + red[3];
        // 2^-64 / S
        out[0] = -logf(total * (5.421010862427522e-20f / (float)S));
    }
}

extern "C" void kernel_launch(void* const* d_in, const int* in_sizes, int n_in,
                              void* d_out, int out_size, void* d_ws, size_t ws_size,
                              hipStream_t stream) {
    const float* img = (const float*)d_in[0];
    const float* gt  = (const float*)d_in[1];

    float* ws        = (float*)d_ws;
    float* meanT     = ws;                  // 256 f
    float* rowmin    = ws + 256;            // S f
    float* rowsum    = rowmin + S;          // S f
    float* colmaxLog = rowsum + S;          // S f
    __hip_bfloat16* A = (__hip_bfloat16*)(colmaxLog + S);
    __hip_bfloat16* B = A + (size_t)S * C;
    __hip_bfloat16* Q = B + (size_t)S * C;   // 170 MB (fits: proven in r4)
    float* ssqP = (float*)Q;                 // [16][S] partials, dead before Q written
    float* out = (float*)d_out;

    k_mean <<<C, 256, 0, stream>>>(gt, meanT);
    k_ssq  <<<288, 256, 0, stream>>>(img, gt, meanT, ssqP);
    k_init <<<(S + 255) / 256, 256, 0, stream>>>(rowmin, rowsum, colmaxLog);
    k_write<<<288, 256, 0, stream>>>(img, gt, meanT, ssqP, A, B);

    k_gemm_store<<<864, 256, 0, stream>>>(A, B, rowmin, Q);
    k_rowsum<<<1152, 256, 0, stream>>>(Q, rowmin, rowsum);
    k_colmax<<<1152, 256, 0, stream>>>(Q, rowmin, rowsum, colmaxLog);

    k_final<<<1, 256, 0, stream>>>(colmaxLog, out);
}

// Round 9
// 218.949 us; speedup vs baseline: 1.3259x; 1.3259x over previous
//
#include <hip/hip_runtime.h>
#include <hip/hip_bf16.h>

#define S 9216      // 96*96 spatial positions
#define C 256       // channels
#define NCT 6       // 256-col tiles per block (block = 64 rows x 1536 cols)
#define NG  (NCT*8) // kt-steps per block (48)
#define SCH 1152    // s-chunk for rowsum/colmax kernels

typedef __bf16 bf16x8 __attribute__((ext_vector_type(8)));
typedef float f32x4 __attribute__((ext_vector_type(4)));
typedef unsigned short us8 __attribute__((ext_vector_type(8)));
typedef unsigned short us4 __attribute__((ext_vector_type(4)));

#define GLOAD_LDS16(g, l) __builtin_amdgcn_global_load_lds( \
    (const __attribute__((address_space(1))) void*)(g),     \
    (__attribute__((address_space(3))) void*)(l), 16, 0, 0)

#define A2C 2.8853900817779268f   // 2*log2(e) = 2/ln2

__device__ __forceinline__ float bf2f(unsigned short u) {
    return __uint_as_float(((unsigned)u) << 16);
}
__device__ __forceinline__ unsigned short f2bfbits(float x) {
    __hip_bfloat16 h = __float2bfloat16(x);
    return *reinterpret_cast<unsigned short*>(&h);
}

// ---------------- mean of gt over spatial, per channel ----------------
__global__ __launch_bounds__(256) void k_mean(const float* __restrict__ gt,
                                              float* __restrict__ meanT) {
    const int c = blockIdx.x;
    const float* p = gt + (size_t)c * S;
    float s = 0.f;
    for (int i = threadIdx.x; i < S; i += 256) s += p[i];
    for (int m = 1; m < 64; m <<= 1) s += __shfl_xor(s, m, 64);
    __shared__ float red[4];
    if ((threadIdx.x & 63) == 0) red[threadIdx.x >> 6] = s;
    __syncthreads();
    if (threadIdx.x == 0)
        meanT[c] = (red[0] + red[1] + red[2] + red[3]) * (1.0f / S);
}

// ------- partial centered sum-of-squares (+ fused reduction-buffer init) ----
__global__ __launch_bounds__(256) void k_ssq(const float* __restrict__ img,
                                             const float* __restrict__ gt,
                                             const float* __restrict__ meanT,
                                             float* __restrict__ ssqP,     // [16][S]
                                             float* __restrict__ rowmin,
                                             float* __restrict__ rowsum,
                                             float* __restrict__ colmaxLog) {
    __shared__ float sm[32];
    const int part = blockIdx.x & 7;
    const int sb   = blockIdx.x >> 3;
    const int t    = threadIdx.x;
    if (t < 32) sm[t] = meanT[part * 32 + t];
    const int s = sb * 256 + t;
    if (part == 0) {           // 36 blocks x 256 threads = S inits
        rowmin[s]    = __uint_as_float(0x7f800000u);  // +inf
        rowsum[s]    = 0.f;
        colmaxLog[s] = 0.f;    // biased log2 max; 0 == 2^-64 ~ 0
    }
    __syncthreads();
    float si = 0.f, st = 0.f;
    #pragma unroll 8
    for (int k = 0; k < 32; ++k) {
        const int c = part * 32 + k;
        const float m  = sm[k];
        const float di = img[(size_t)c * S + s] - m;
        const float dt = gt [(size_t)c * S + s] - m;
        si += di * di;
        st += dt * dt;
    }
    ssqP[(size_t)part * S + s]       = si;
    ssqP[(size_t)(part + 8) * S + s] = st;
}

// ---------------- write normalized bf16 A,B (transposed to [S][C]) --------
__global__ __launch_bounds__(256) void k_write(const float* __restrict__ img,
                                               const float* __restrict__ gt,
                                               const float* __restrict__ meanT,
                                               const float* __restrict__ ssqP,
                                               __hip_bfloat16* __restrict__ A,
                                               __hip_bfloat16* __restrict__ B) {
    __shared__ float sm[32];
    const int part = blockIdx.x & 7;
    const int sb   = blockIdx.x >> 3;
    const int t    = threadIdx.x;
    if (t < 32) sm[t] = meanT[part * 32 + t];
    __syncthreads();
    const int s = sb * 256 + t;
    float si = 0.f, st = 0.f;
    #pragma unroll
    for (int p = 0; p < 8; ++p) {
        si += ssqP[(size_t)p * S + s];
        st += ssqP[(size_t)(p + 8) * S + s];
    }
    const float ri = 1.0f / fmaxf(sqrtf(si), 1e-12f);
    const float rt = 1.0f / fmaxf(sqrtf(st), 1e-12f);
    const int c0 = part * 32;
    #pragma unroll
    for (int cc = 0; cc < 4; ++cc) {
        us8 va, vb;
        #pragma unroll
        for (int e = 0; e < 8; ++e) {
            const int c = c0 + cc * 8 + e;
            const float m = sm[cc * 8 + e];
            va[e] = f2bfbits((img[(size_t)c * S + s] - m) * ri);
            vb[e] = f2bfbits((gt [(size_t)c * S + s] - m) * rt);
        }
        *reinterpret_cast<us8*>(A + (size_t)s * C + c0 + cc * 8) = va;
        *reinterpret_cast<us8*>(B + (size_t)s * C + c0 + cc * 8) = vb;
    }
}

// ---------------- GEMM pass: store raw^T + rowmin ----------------
// r7 core (A 64-row panel full-K in LDS + B 256-col double-buffered stages,
// 64KB LDS) with two fixes:
//  (a) store-aware counted vmcnt: per-tile waits [20,20,4,...] so the next
//      tile's stage waits do NOT force the epilogue store burst (16 us4
//      stores/wave, in-order vmcnt retire) to drain first;
//  (b) rowmin atomics deferred to kernel end (persistent vmin regs) so only
//      plain stores sit in the vmcnt window;
// plus 864 blocks (64x1536 each) so every CU holds 2 blocks (r7's 432-block
// grid left a third of CUs with no overlap partner).
__global__ __launch_bounds__(256, 2) void k_gemm_store(const __hip_bfloat16* __restrict__ A,
                                                       const __hip_bfloat16* __restrict__ B,
                                                       float* __restrict__ rowmin,
                                                       __hip_bfloat16* __restrict__ Q) {
    __shared__ alignas(16) __hip_bfloat16 As[64 * 256];       // 32 KB
    __shared__ alignas(16) __hip_bfloat16 Bs[2 * 256 * 32];   // 32 KB
    const int tid  = threadIdx.x;
    const int lane = tid & 63;
    const int wid  = tid >> 6;       // wave owns 64-col strip wid*64 of the stage
    // 864 = 8 XCDs x (6 colGroups x 18 strips): co-resident blocks on an XCD
    // share one colGroup (B slice 786KB) + an 18-strip A window (~576KB) < L2.
    const int orig = blockIdx.x;
    const int xcd  = orig & 7;
    const int q    = orig >> 3;                  // 0..107
    const int colGroup = q / 18;                 // 0..5
    const int strip    = xcd * 18 + (q % 18);    // 0..143
    const int rowBase = strip * 64;
    const int cb0     = colGroup * 1536;

    const int frow = lane & 15;
    const int kgrp = lane >> 4;

    // ---- stage A (full K, 8 loads/thread)
    {
        const int arow_lo = lane >> 5;
        const int achunk  = lane & 31;
        #pragma unroll
        for (int j = 0; j < 8; ++j) {
            const int row = wid * 16 + j * 2 + arow_lo;
            const int cc  = achunk ^ (row & 7);
            GLOAD_LDS16(A + (size_t)(rowBase + row) * C + cc * 8,
                        &As[(wid * 16 + j * 2) * 256 + lane * 8]);
        }
    }
    // ---- B prologue: stages g=0,1 (4 loads/thread each)
    const int bcol_lo = lane >> 2;
    const int bchunk  = (lane & 3) ^ ((lane >> 3) & 3);
    #pragma unroll
    for (int g = 0; g < 2; ++g) {
        const int cb = cb0 + (g >> 3) * 256;
        const int kt = g & 7;
        #pragma unroll
        for (int i = 0; i < 4; ++i) {
            const int col = wid * 16 + i * 64 + bcol_lo;
            GLOAD_LDS16(B + (size_t)(cb + col) * C + kt * 32 + bchunk * 8,
                        &Bs[(g & 1) * 8192 + wid * 512 + i * 2048 + lane * 8]);
        }
    }

    const int bswz = (kgrp ^ ((frow >> 1) & 3)) * 8;

    // persistent row-min across all tiles (atomics once at kernel end)
    float vmin[4][4];
    #pragma unroll
    for (int m = 0; m < 4; ++m)
        #pragma unroll
        for (int qq = 0; qq < 4; ++qq) vmin[m][qq] = 1e30f;

    for (int t = 0; t < NCT; ++t) {
        f32x4 acc[4][4] = {};
        #pragma unroll
        for (int kt = 0; kt < 8; ++kt) {
            const int g = t * 8 + kt;
            // store-aware counted waits:
            //  tiles>0, kt 0/1: window = [stg kt][stg kt+1 | stores(16)] -> 20
            //  otherwise steady: 1 newer stage in flight -> 4; last kt -> 0
            if (kt < 2 && t > 0)      asm volatile("s_waitcnt vmcnt(20)" ::: "memory");
            else if (g < NG - 1)      asm volatile("s_waitcnt vmcnt(4)"  ::: "memory");
            else                      asm volatile("s_waitcnt vmcnt(0)"  ::: "memory");
            __builtin_amdgcn_s_barrier();

            bf16x8 af[4], bfr[4];
            #pragma unroll
            for (int m = 0; m < 4; ++m) {
                const int row = m * 16 + frow;
                const int p   = (kt * 4 + kgrp) ^ (frow & 7);
                af[m] = *reinterpret_cast<const bf16x8*>(&As[row * 256 + p * 8]);
            }
            const int bbase = (g & 1) * 8192;
            #pragma unroll
            for (int n = 0; n < 4; ++n) {
                const int col = wid * 64 + n * 16 + frow;
                bfr[n] = *reinterpret_cast<const bf16x8*>(&Bs[bbase + col * 32 + bswz]);
            }
            #pragma unroll
            for (int m = 0; m < 4; ++m)
                #pragma unroll
                for (int n = 0; n < 4; ++n)
                    acc[m][n] = __builtin_amdgcn_mfma_f32_16x16x32_bf16(af[m], bfr[n], acc[m][n], 0, 0, 0);

            __builtin_amdgcn_s_barrier();

            if (g + 2 < NG) {
                const int g2 = g + 2;
                const int cb = cb0 + (g2 >> 3) * 256;
                const int k2 = g2 & 7;
                #pragma unroll
                for (int i = 0; i < 4; ++i) {
                    const int col = wid * 16 + i * 64 + bcol_lo;
                    GLOAD_LDS16(B + (size_t)(cb + col) * C + k2 * 32 + bchunk * 8,
                                &Bs[(g2 & 1) * 8192 + wid * 512 + i * 2048 + lane * 8]);
                }
            }
        }

        // ---- epilogue tile t: 16 plain us4 stores/wave (no atomics here)
        // C/D map: r_local = m*16 + kgrp*4 + q, col = colBase + n*16 + frow
        const int colBase = cb0 + t * 256;
        #pragma unroll
        for (int n = 0; n < 4; ++n) {
            const int cg = colBase + wid * 64 + n * 16 + frow;
            #pragma unroll
            for (int m = 0; m < 4; ++m) {
                us4 pk;
                #pragma unroll
                for (int qq = 0; qq < 4; ++qq) {
                    const float raw = fmaxf(0.5f * (1.0f - acc[m][n][qq]), 0.0f);
                    vmin[m][qq] = fminf(vmin[m][qq], raw);
                    pk[qq] = f2bfbits(raw);
                }
                *reinterpret_cast<us4*>(Q + (size_t)cg * S + rowBase + m * 16 + kgrp * 4) = pk;
            }
        }
    }

    // ---- deferred rowmin atomics (once per block)
    #pragma unroll
    for (int m = 0; m < 4; ++m)
        #pragma unroll
        for (int qq = 0; qq < 4; ++qq) {
            float v = vmin[m][qq];
            v = fminf(v, __shfl_xor(v, 1, 64));
            v = fminf(v, __shfl_xor(v, 2, 64));
            v = fminf(v, __shfl_xor(v, 4, 64));
            v = fminf(v, __shfl_xor(v, 8, 64));
            if (frow == 0)
                atomicMin((unsigned int*)&rowmin[rowBase + m * 16 + kgrp * 4 + qq],
                          __float_as_uint(v));
        }
}

// ---------------- rowsum over s-chunks (exp2 form) ------------
__global__ __launch_bounds__(256) void k_rowsum(const __hip_bfloat16* __restrict__ Q,
                                                const float* __restrict__ rowmin,
                                                float* __restrict__ rowsum) {
    __shared__ float sBrN[64];   // -A2C / (rowmin+eps)
    __shared__ float srs[64];
    const int t  = threadIdx.x;
    const int r0 = (blockIdx.x >> 3) * 64;
    const int s0 = (blockIdx.x & 7) * SCH;
    if (t < 64) {
        sBrN[t] = -A2C / (rowmin[r0 + t] + 1e-5f);
        srs[t]  = 0.f;
    }
    __syncthreads();
    const int roct = (t & 7) * 8;
    const int ss   = t >> 3;          // 0..31
    float brn[8];
    #pragma unroll
    for (int j = 0; j < 8; ++j) brn[j] = sBrN[roct + j];
    const __hip_bfloat16* base = Q + r0 + roct;

    float sums[8] = {};
    #pragma unroll 4
    for (int i = 0; i < SCH / 32; ++i) {
        const int s = s0 + ss + i * 32;
        const us8 v = *reinterpret_cast<const us8*>(base + (size_t)s * S);
        #pragma unroll
        for (int j = 0; j < 8; ++j)
            sums[j] += exp2f(fmaf(brn[j], bf2f(v[j]), A2C));
    }
    #pragma unroll
    for (int j = 0; j < 8; ++j) {
        float x = sums[j];
        x += __shfl_xor(x, 8, 64);
        x += __shfl_xor(x, 16, 64);
        x += __shfl_xor(x, 32, 64);
        if ((t & 63) < 8) atomicAdd(&srs[roct + j], x);
    }
    __syncthreads();
    if (t < 64) atomicAdd(&rowsum[r0 + t], srs[t]);
}

// ---------------- colmax in LOG space (3 ops/elem, no exp) ----------------
__global__ __launch_bounds__(256) void k_colmax(const __hip_bfloat16* __restrict__ Q,
                                                const float* __restrict__ rowmin,
                                                const float* __restrict__ rowsum,
                                                float* __restrict__ colmaxLog) {
    __shared__ float sBrN[64];
    __shared__ float sCA[64];
    const int t  = threadIdx.x;
    const int r0 = (blockIdx.x >> 3) * 64;
    const int s0 = (blockIdx.x & 7) * SCH;
    if (t < 64) {
        sBrN[t] = -A2C / (rowmin[r0 + t] + 1e-5f);
        sCA[t]  = A2C + 64.0f - __log2f(rowsum[r0 + t]);
    }
    __syncthreads();
    const int roct = (t & 7) * 8;
    const int ss   = t >> 3;
    float brn[8], ca[8];
    #pragma unroll
    for (int j = 0; j < 8; ++j) { brn[j] = sBrN[roct + j]; ca[j] = sCA[roct + j]; }
    const __hip_bfloat16* base = Q + r0 + roct;

    #pragma unroll 4
    for (int i = 0; i < SCH / 32; ++i) {
        const int s = s0 + ss + i * 32;
        const us8 v = *reinterpret_cast<const us8*>(base + (size_t)s * S);
        float mx = -1e30f;
        #pragma unroll
        for (int j = 0; j < 8; ++j)
            mx = fmaxf(mx, fmaf(brn[j], bf2f(v[j]), ca[j]));
        mx = fmaxf(mx, __shfl_xor(mx, 1, 64));
        mx = fmaxf(mx, __shfl_xor(mx, 2, 64));
        mx = fmaxf(mx, __shfl_xor(mx, 4, 64));
        if ((t & 7) == 0)
            atomicMax((unsigned int*)&colmaxLog[s], __float_as_uint(fmaxf(mx, 0.0f)));
    }
}

// ---------------- final: loss = -log(mean_s 2^(cl[s]-64)) ----------------
__global__ __launch_bounds__(256) void k_final(const float* __restrict__ colmaxLog,
                                               float* __restrict__ out) {
    float s = 0.f;
    for (int i = threadIdx.x; i < S; i += 256) s += exp2f(colmaxLog[i]);
    for (int m = 1; m < 64; m <<= 1) s += __shfl_xor(s, m, 64);
    __shared__ float red[4];
    if ((threadIdx.x & 63) == 0) red[threadIdx.x >> 6] = s;
    __syncthreads();
    if (threadIdx.x == 0) {
        const float total = red[0] + red[1] + red[2] + red[3];
        // 2^-64 / S
        out[0] = -logf(total * (5.421010862427522e-20f / (float)S));
    }
}

extern "C" void kernel_launch(void* const* d_in, const int* in_sizes, int n_in,
                              void* d_out, int out_size, void* d_ws, size_t ws_size,
                              hipStream_t stream) {
    const float* img = (const float*)d_in[0];
    const float* gt  = (const float*)d_in[1];

    float* ws        = (float*)d_ws;
    float* meanT     = ws;                  // 256 f
    float* rowmin    = ws + 256;            // S f
    float* rowsum    = rowmin + S;          // S f
    float* colmaxLog = rowsum + S;          // S f
    __hip_bfloat16* A = (__hip_bfloat16*)(colmaxLog + S);
    __hip_bfloat16* B = A + (size_t)S * C;
    __hip_bfloat16* Q = B + (size_t)S * C;   // 170 MB (fits: proven in r4)
    float* ssqP = (float*)Q;                 // [16][S] partials, dead before Q written
    float* out = (float*)d_out;

    k_mean <<<C, 256, 0, stream>>>(gt, meanT);
    k_ssq  <<<288, 256, 0, stream>>>(img, gt, meanT, ssqP, rowmin, rowsum, colmaxLog);
    k_write<<<288, 256, 0, stream>>>(img, gt, meanT, ssqP, A, B);

    k_gemm_store<<<864, 256, 0, stream>>>(A, B, rowmin, Q);
    k_rowsum<<<1152, 256, 0, stream>>>(Q, rowmin, rowsum);
    k_colmax<<<1152, 256, 0, stream>>>(Q, rowmin, rowsum, colmaxLog);

    k_final<<<1, 256, 0, stream>>>(colmaxLog, out);
}

// Round 10
// 214.735 us; speedup vs baseline: 1.3520x; 1.0196x over previous
//
#include <hip/hip_runtime.h>
#include <hip/hip_bf16.h>

#define S 9216      // 96*96 spatial positions
#define C 256       // channels
#define NCT 6       // 256-col tiles per block (block = 64 rows x 1536 cols)
#define NG  (NCT*8) // kt-steps per block (48)
#define SCH 1152    // s-chunk for rowsum/colmax kernels

typedef __bf16 bf16x8 __attribute__((ext_vector_type(8)));
typedef float f32x4 __attribute__((ext_vector_type(4)));
typedef unsigned short us8 __attribute__((ext_vector_type(8)));
typedef unsigned short us4 __attribute__((ext_vector_type(4)));

#define GLOAD_LDS16(g, l) __builtin_amdgcn_global_load_lds( \
    (const __attribute__((address_space(1))) void*)(g),     \
    (__attribute__((address_space(3))) void*)(l), 16, 0, 0)

#define A2C 2.8853900817779268f   // 2*log2(e) = 2/ln2

__device__ __forceinline__ float bf2f(unsigned short u) {
    return __uint_as_float(((unsigned)u) << 16);
}
__device__ __forceinline__ unsigned short f2bfbits(float x) {
    __hip_bfloat16 h = __float2bfloat16(x);
    return *reinterpret_cast<unsigned short*>(&h);
}

// ---------------- mean of gt over spatial, per channel ----------------
__global__ __launch_bounds__(256) void k_mean(const float* __restrict__ gt,
                                              float* __restrict__ meanT) {
    const int c = blockIdx.x;
    const float* p = gt + (size_t)c * S;
    float s = 0.f;
    for (int i = threadIdx.x; i < S; i += 256) s += p[i];
    for (int m = 1; m < 64; m <<= 1) s += __shfl_xor(s, m, 64);
    __shared__ float red[4];
    if ((threadIdx.x & 63) == 0) red[threadIdx.x >> 6] = s;
    __syncthreads();
    if (threadIdx.x == 0)
        meanT[c] = (red[0] + red[1] + red[2] + red[3]) * (1.0f / S);
}

// ------- partial centered sum-of-squares (+ fused reduction-buffer init) ----
__global__ __launch_bounds__(256) void k_ssq(const float* __restrict__ img,
                                             const float* __restrict__ gt,
                                             const float* __restrict__ meanT,
                                             float* __restrict__ ssqP,     // [16][S]
                                             float* __restrict__ rowmin,
                                             float* __restrict__ rowsum,
                                             float* __restrict__ colmaxLog) {
    __shared__ float sm[32];
    const int part = blockIdx.x & 7;
    const int sb   = blockIdx.x >> 3;
    const int t    = threadIdx.x;
    if (t < 32) sm[t] = meanT[part * 32 + t];
    const int s = sb * 256 + t;
    if (part == 0) {           // 36 blocks x 256 threads = S inits
        rowmin[s]    = __uint_as_float(0x7f800000u);  // +inf
        rowsum[s]    = 0.f;
        colmaxLog[s] = 0.f;    // biased log2 max; 0 == 2^-64 ~ 0
    }
    __syncthreads();
    float si = 0.f, st = 0.f;
    #pragma unroll 8
    for (int k = 0; k < 32; ++k) {
        const int c = part * 32 + k;
        const float m  = sm[k];
        const float di = img[(size_t)c * S + s] - m;
        const float dt = gt [(size_t)c * S + s] - m;
        si += di * di;
        st += dt * dt;
    }
    ssqP[(size_t)part * S + s]       = si;
    ssqP[(size_t)(part + 8) * S + s] = st;
}

// ---------------- write normalized bf16 A,B (transposed to [S][C]) --------
__global__ __launch_bounds__(256) void k_write(const float* __restrict__ img,
                                               const float* __restrict__ gt,
                                               const float* __restrict__ meanT,
                                               const float* __restrict__ ssqP,
                                               __hip_bfloat16* __restrict__ A,
                                               __hip_bfloat16* __restrict__ B) {
    __shared__ float sm[32];
    const int part = blockIdx.x & 7;
    const int sb   = blockIdx.x >> 3;
    const int t    = threadIdx.x;
    if (t < 32) sm[t] = meanT[part * 32 + t];
    __syncthreads();
    const int s = sb * 256 + t;
    float si = 0.f, st = 0.f;
    #pragma unroll
    for (int p = 0; p < 8; ++p) {
        si += ssqP[(size_t)p * S + s];
        st += ssqP[(size_t)(p + 8) * S + s];
    }
    const float ri = 1.0f / fmaxf(sqrtf(si), 1e-12f);
    const float rt = 1.0f / fmaxf(sqrtf(st), 1e-12f);
    const int c0 = part * 32;
    #pragma unroll
    for (int cc = 0; cc < 4; ++cc) {
        us8 va, vb;
        #pragma unroll
        for (int e = 0; e < 8; ++e) {
            const int c = c0 + cc * 8 + e;
            const float m = sm[cc * 8 + e];
            va[e] = f2bfbits((img[(size_t)c * S + s] - m) * ri);
            vb[e] = f2bfbits((gt [(size_t)c * S + s] - m) * rt);
        }
        *reinterpret_cast<us8*>(A + (size_t)s * C + c0 + cc * 8) = va;
        *reinterpret_cast<us8*>(B + (size_t)s * C + c0 + cc * 8) = vb;
    }
}

// ---------------- GEMM pass: store raw^T + rowmin ----------------
// BARRIER-FREE K-loop. A (64 rows x full K, 32KB) staged once (one barrier).
// Each wave stages ONLY its own 64 B-columns into a private 3-buffer LDS ring
// (3 x 4KB/wave; total LDS 80KB -> 2 blocks/CU). gload_lds -> own ds_read
// ordering is per-wave counted vmcnt; no cross-wave sharing of B, so waves
// run self-paced, overlapping MFMA and VMEM across waves (m114) instead of
// lockstep-draining 96 barriers (the 4-round-invariant ~13-16% MfmaUtil wall).
// Buffer g+3 reuses buf g%3: fenced by lgkmcnt(0)+sched_barrier(0) after the
// ds_reads (rule 18), then the 16 MFMAs hide the stage latency.
__global__ __launch_bounds__(256, 2) void k_gemm_store(const __hip_bfloat16* __restrict__ A,
                                                       const __hip_bfloat16* __restrict__ B,
                                                       float* __restrict__ rowmin,
                                                       __hip_bfloat16* __restrict__ Q) {
    __shared__ alignas(16) __hip_bfloat16 As[64 * 256];        // 32 KB
    __shared__ alignas(16) __hip_bfloat16 Bs[4 * 3 * 2048];    // 48 KB (4 waves x 3 bufs x 64x32)
    const int tid  = threadIdx.x;
    const int lane = tid & 63;
    const int wid  = tid >> 6;
    // 864 = 8 XCDs x (6 colGroups x 18 strips)
    const int orig = blockIdx.x;
    const int xcd  = orig & 7;
    const int q    = orig >> 3;                  // 0..107
    const int colGroup = q / 18;                 // 0..5
    const int strip    = xcd * 18 + (q % 18);    // 0..143
    const int rowBase = strip * 64;
    const int cb0     = colGroup * 1536;

    const int frow = lane & 15;
    const int kgrp = lane >> 4;

    // ---- stage A (full K, 8 loads/thread)
    {
        const int arow_lo = lane >> 5;
        const int achunk  = lane & 31;
        #pragma unroll
        for (int j = 0; j < 8; ++j) {
            const int row = wid * 16 + j * 2 + arow_lo;
            const int cc  = achunk ^ (row & 7);
            GLOAD_LDS16(A + (size_t)(rowBase + row) * C + cc * 8,
                        &As[(wid * 16 + j * 2) * 256 + lane * 8]);
        }
    }

    // ---- per-wave B staging: wave's own 64 cols, source pre-swizzled so the
    // linear LDS write [col][chunk] holds chunk^((col>>1)&3) (read-side bswz).
    const int bcol4  = lane >> 2;                       // col within 16-col group
    const int bchunk = (lane & 3) ^ ((lane >> 3) & 3);  // pre-swizzled k-chunk
    __hip_bfloat16* const BsW = &Bs[wid * 6144];
    const __hip_bfloat16* const Bsrc = B + (size_t)(cb0 + wid * 64) * C;

#define STAGE_B(tt, kk, bb) do {                                              \
    _Pragma("unroll")                                                         \
    for (int i_ = 0; i_ < 4; ++i_) {                                          \
        GLOAD_LDS16(Bsrc + (size_t)((tt) * 256 + i_ * 16 + bcol4) * C         \
                         + (kk) * 32 + bchunk * 8,                            \
                    &BsW[(bb) * 2048 + i_ * 512]);                            \
    } } while (0)

    // prologue: stages g=0,1,2 -> bufs 0,1,2
    STAGE_B(0, 0, 0);
    STAGE_B(0, 1, 1);
    STAGE_B(0, 2, 2);

    // A(8) oldest, B(12) newer: vmcnt(12) = A retired; barrier for cross-wave A.
    asm volatile("s_waitcnt vmcnt(12)" ::: "memory");
    __builtin_amdgcn_s_barrier();

    const int bswz = (kgrp ^ ((frow >> 1) & 3)) * 8;

    float vmin[4][4];
    #pragma unroll
    for (int m = 0; m < 4; ++m)
        #pragma unroll
        for (int qq = 0; qq < 4; ++qq) vmin[m][qq] = 1e30f;

    int b0 = 0;   // buf index of kt=0 for current tile == (t*8)%3
    for (int t = 0; t < NCT; ++t) {
        f32x4 acc[4][4] = {};
        #pragma unroll
        for (int kt = 0; kt < 8; ++kt) {
            // exact in-order vmcnt windows (stage loads 4 each + 16 stores):
            //  kt0-2: newer = 2 stages (8) [+16 stores if t>0] -> 24 / 8
            //  kt3-5: newer = 2 stages -> 8 (kt3 also drains prior stores)
            //  kt6:   tail tile has only 1 newer stage -> 4, else 8
            //  kt7:   tail none -> 0, else 8
            if (kt < 3) {
                if (t) asm volatile("s_waitcnt vmcnt(24)" ::: "memory");
                else   asm volatile("s_waitcnt vmcnt(8)"  ::: "memory");
            } else if (kt < 6) {
                asm volatile("s_waitcnt vmcnt(8)" ::: "memory");
            } else if (kt == 6) {
                if (t == NCT - 1) asm volatile("s_waitcnt vmcnt(4)" ::: "memory");
                else              asm volatile("s_waitcnt vmcnt(8)" ::: "memory");
            } else {
                if (t == NCT - 1) asm volatile("s_waitcnt vmcnt(0)" ::: "memory");
                else              asm volatile("s_waitcnt vmcnt(8)" ::: "memory");
            }

            int bufc = b0 + (kt % 3);
            if (bufc >= 3) bufc -= 3;

            bf16x8 af[4], bfr[4];
            #pragma unroll
            for (int m = 0; m < 4; ++m) {
                const int row = m * 16 + frow;
                const int p   = (kt * 4 + kgrp) ^ (frow & 7);
                af[m] = *reinterpret_cast<const bf16x8*>(&As[row * 256 + p * 8]);
            }
            #pragma unroll
            for (int n = 0; n < 4; ++n)
                bfr[n] = *reinterpret_cast<const bf16x8*>(
                    &BsW[bufc * 2048 + (n * 16 + frow) * 32 + bswz]);

            // fence: ds_reads complete before buf[bufc] is overwritten below
            asm volatile("s_waitcnt lgkmcnt(0)" ::: "memory");
            __builtin_amdgcn_sched_barrier(0);

            // issue stage g+3 into the buffer just consumed (no barrier!)
            if (kt <= 4) {
                STAGE_B(t, kt + 3, bufc);
            } else if (t + 1 < NCT) {
                STAGE_B(t + 1, kt - 5, bufc);
            }

            #pragma unroll
            for (int m = 0; m < 4; ++m)
                #pragma unroll
                for (int n = 0; n < 4; ++n)
                    acc[m][n] = __builtin_amdgcn_mfma_f32_16x16x32_bf16(af[m], bfr[n], acc[m][n], 0, 0, 0);
        }
        b0 += 2; if (b0 >= 3) b0 -= 3;   // (t*8)%3 advances by 2 per tile

        // ---- epilogue tile t: 16 plain us4 stores/wave (atomics deferred)
        // C/D map: r_local = m*16 + kgrp*4 + q, col = cb0 + t*256 + wid*64 + n*16 + frow
        const int colBase = cb0 + t * 256;
        #pragma unroll
        for (int n = 0; n < 4; ++n) {
            const int cg = colBase + wid * 64 + n * 16 + frow;
            #pragma unroll
            for (int m = 0; m < 4; ++m) {
                us4 pk;
                #pragma unroll
                for (int qq = 0; qq < 4; ++qq) {
                    const float raw = fmaxf(0.5f * (1.0f - acc[m][n][qq]), 0.0f);
                    vmin[m][qq] = fminf(vmin[m][qq], raw);
                    pk[qq] = f2bfbits(raw);
                }
                *reinterpret_cast<us4*>(Q + (size_t)cg * S + rowBase + m * 16 + kgrp * 4) = pk;
            }
        }
    }
#undef STAGE_B

    // ---- deferred rowmin atomics (once per block)
    #pragma unroll
    for (int m = 0; m < 4; ++m)
        #pragma unroll
        for (int qq = 0; qq < 4; ++qq) {
            float v = vmin[m][qq];
            v = fminf(v, __shfl_xor(v, 1, 64));
            v = fminf(v, __shfl_xor(v, 2, 64));
            v = fminf(v, __shfl_xor(v, 4, 64));
            v = fminf(v, __shfl_xor(v, 8, 64));
            if (frow == 0)
                atomicMin((unsigned int*)&rowmin[rowBase + m * 16 + kgrp * 4 + qq],
                          __float_as_uint(v));
        }
}

// ---------------- rowsum over s-chunks (exp2 form) ------------
__global__ __launch_bounds__(256) void k_rowsum(const __hip_bfloat16* __restrict__ Q,
                                                const float* __restrict__ rowmin,
                                                float* __restrict__ rowsum) {
    __shared__ float sBrN[64];   // -A2C / (rowmin+eps)
    __shared__ float srs[64];
    const int t  = threadIdx.x;
    const int r0 = (blockIdx.x >> 3) * 64;
    const int s0 = (blockIdx.x & 7) * SCH;
    if (t < 64) {
        sBrN[t] = -A2C / (rowmin[r0 + t] + 1e-5f);
        srs[t]  = 0.f;
    }
    __syncthreads();
    const int roct = (t & 7) * 8;
    const int ss   = t >> 3;          // 0..31
    float brn[8];
    #pragma unroll
    for (int j = 0; j < 8; ++j) brn[j] = sBrN[roct + j];
    const __hip_bfloat16* base = Q + r0 + roct;

    float sums[8] = {};
    #pragma unroll 4
    for (int i = 0; i < SCH / 32; ++i) {
        const int s = s0 + ss + i * 32;
        const us8 v = *reinterpret_cast<const us8*>(base + (size_t)s * S);
        #pragma unroll
        for (int j = 0; j < 8; ++j)
            sums[j] += exp2f(fmaf(brn[j], bf2f(v[j]), A2C));
    }
    #pragma unroll
    for (int j = 0; j < 8; ++j) {
        float x = sums[j];
        x += __shfl_xor(x, 8, 64);
        x += __shfl_xor(x, 16, 64);
        x += __shfl_xor(x, 32, 64);
        if ((t & 63) < 8) atomicAdd(&srs[roct + j], x);
    }
    __syncthreads();
    if (t < 64) atomicAdd(&rowsum[r0 + t], srs[t]);
}

// ---------------- colmax in LOG space (3 ops/elem, no exp) ----------------
__global__ __launch_bounds__(256) void k_colmax(const __hip_bfloat16* __restrict__ Q,
                                                const float* __restrict__ rowmin,
                                                const float* __restrict__ rowsum,
                                                float* __restrict__ colmaxLog) {
    __shared__ float sBrN[64];
    __shared__ float sCA[64];
    const int t  = threadIdx.x;
    const int r0 = (blockIdx.x >> 3) * 64;
    const int s0 = (blockIdx.x & 7) * SCH;
    if (t < 64) {
        sBrN[t] = -A2C / (rowmin[r0 + t] + 1e-5f);
        sCA[t]  = A2C + 64.0f - __log2f(rowsum[r0 + t]);
    }
    __syncthreads();
    const int roct = (t & 7) * 8;
    const int ss   = t >> 3;
    float brn[8], ca[8];
    #pragma unroll
    for (int j = 0; j < 8; ++j) { brn[j] = sBrN[roct + j]; ca[j] = sCA[roct + j]; }
    const __hip_bfloat16* base = Q + r0 + roct;

    #pragma unroll 4
    for (int i = 0; i < SCH / 32; ++i) {
        const int s = s0 + ss + i * 32;
        const us8 v = *reinterpret_cast<const us8*>(base + (size_t)s * S);
        float mx = -1e30f;
        #pragma unroll
        for (int j = 0; j < 8; ++j)
            mx = fmaxf(mx, fmaf(brn[j], bf2f(v[j]), ca[j]));
        mx = fmaxf(mx, __shfl_xor(mx, 1, 64));
        mx = fmaxf(mx, __shfl_xor(mx, 2, 64));
        mx = fmaxf(mx, __shfl_xor(mx, 4, 64));
        if ((t & 7) == 0)
            atomicMax((unsigned int*)&colmaxLog[s], __float_as_uint(fmaxf(mx, 0.0f)));
    }
}

// ---------------- final: loss = -log(mean_s 2^(cl[s]-64)) ----------------
__global__ __launch_bounds__(256) void k_final(const float* __restrict__ colmaxLog,
                                               float* __restrict__ out) {
    float s = 0.f;
    for (int i = threadIdx.x; i < S; i += 256) s += exp2f(colmaxLog[i]);
    for (int m = 1; m < 64; m <<= 1) s += __shfl_xor(s, m, 64);
    __shared__ float red[4];
    if ((threadIdx.x & 63) == 0) red[threadIdx.x >> 6] = s;
    __syncthreads();
    if (threadIdx.x == 0) {
        const float total = red[0] + red[1] + red[2] + red[3];
        // 2^-64 / S
        out[0] = -logf(total * (5.421010862427522e-20f / (float)S));
    }
}

extern "C" void kernel_launch(void* const* d_in, const int* in_sizes, int n_in,
                              void* d_out, int out_size, void* d_ws, size_t ws_size,
                              hipStream_t stream) {
    const float* img = (const float*)d_in[0];
    const float* gt  = (const float*)d_in[1];

    float* ws        = (float*)d_ws;
    float* meanT     = ws;                  // 256 f
    float* rowmin    = ws + 256;            // S f
    float* rowsum    = rowmin + S;          // S f
    float* colmaxLog = rowsum + S;          // S f
    __hip_bfloat16* A = (__hip_bfloat16*)(colmaxLog + S);
    __hip_bfloat16* B = A + (size_t)S * C;
    __hip_bfloat16* Q = B + (size_t)S * C;   // 170 MB (fits: proven in r4)
    float* ssqP = (float*)Q;                 // [16][S] partials, dead before Q written
    float* out = (float*)d_out;

    k_mean <<<C, 256, 0, stream>>>(gt, meanT);
    k_ssq  <<<288, 256, 0, stream>>>(img, gt, meanT, ssqP, rowmin, rowsum, colmaxLog);
    k_write<<<288, 256, 0, stream>>>(img, gt, meanT, ssqP, A, B);

    k_gemm_store<<<864, 256, 0, stream>>>(A, B, rowmin, Q);
    k_rowsum<<<1152, 256, 0, stream>>>(Q, rowmin, rowsum);
    k_colmax<<<1152, 256, 0, stream>>>(Q, rowmin, rowsum, colmaxLog);

    k_final<<<1, 256, 0, stream>>>(colmaxLog, out);
}